// Round 4
// baseline (3556.037 us; speedup 1.0000x reference)
//
#include <hip/hip_runtime.h>

#define T_STEPS 1000
#define BATCH   256
#define IN_DIM  128
#define HID     512
#define OUT_DIM 32
#define ALPHA_F 0.2f
#define OMA_F   0.8f
#define MAXNNZ  96   // Binomial(511,0.1) max over 512 rows ~ 75; 96 is 6.5 sigma

// ---- workspace layout (byte offsets, all 16B aligned) ----
// val_t : float  [HID][MAXNNZ]   rank-ordered rows      @ 0        (196608 B)
// idx_t : ushort [HID][MAXNNZ]   byte offsets (j*4)     @ 196608   (98304 B)
// perm  : uint   [HID]           rank -> row            @ 294912   (2048 B)
// nnzR  : uint   [HID]           nnz sorted ascending   @ 296960   (2048 B)
// w_inT : float  [IN_DIM][HID]                          @ 299008   (262144 B)
// fcT   : float  [HID][OUT_DIM]                         @ 561152   (65536 B)

// ============================================================
// K2: build sparse table (rank-sorted by nnz, DETERMINISTIC tie-
//     break by row index) + transposes. Each row's nnz list is
//     bank-rotation-sorted for its reader lane (rank & 31) so at
//     unrolled gather slot s, lane l hits bank ~ (l + c*s) % 32.
// ============================================================
__global__ __launch_bounds__(512) void build_kernel(
    const float* __restrict__ w_h, const float* __restrict__ dale,
    const float* __restrict__ sparse, const float* __restrict__ w_in,
    const float* __restrict__ fc_w,
    float* __restrict__ val_t, unsigned short* __restrict__ idx_t,
    unsigned int* __restrict__ perm, unsigned int* __restrict__ nnzR,
    float* __restrict__ w_inT, float* __restrict__ fcT)
{
    int tid = threadIdx.x;           // 0..511 = row h
    __shared__ int cnt_sh[HID];

    const float4* wr4 = (const float4*)(w_h    + tid * HID);
    const float4* sr4 = (const float4*)(sparse + tid * HID);

    // pass 1: count nnz of row h
    int cnt = 0;
    for (int j4 = 0; j4 < HID / 4; j4++) {
        float4 w = wr4[j4];
        float4 s = sr4[j4];
        if (w.x > 0.f && s.x > 0.5f) cnt++;
        if (w.y > 0.f && s.y > 0.5f) cnt++;
        if (w.z > 0.f && s.z > 0.5f) cnt++;
        if (w.w > 0.f && s.w > 0.5f) cnt++;
    }
    int c = min(cnt, MAXNNZ);

    // deterministic rank: stable sort by (c, h)
    cnt_sh[tid] = c;
    __syncthreads();
    int rank = 0;
    for (int j = 0; j < HID; j++) {
        int cj = cnt_sh[j];                     // broadcast read
        rank += (cj < c) || (cj == c && j < tid);
    }
    perm[rank] = (unsigned int)tid;
    nnzR[rank] = (unsigned int)c;

    // pass 2: fill row table at rank-ordered position
    float*          vout = val_t + rank * MAXNNZ;
    unsigned short* iout = idx_t + rank * MAXNNZ;
    int k = 0;
    for (int j = 0; j < HID && k < MAXNNZ; j++) {
        float w = w_h[tid * HID + j];
        float s = sparse[tid * HID + j];
        if (w > 0.f && s > 0.5f) {
            vout[k] = w * dale[j];
            iout[k] = (unsigned short)(j * 4);   // LDS byte offset
            k++;
        }
    }
    for (; k < MAXNNZ; k++) { vout[k] = 0.f; iout[k] = 0; }

    // pass 3: bank-rotation insertion sort of [0..c) for reader lane
    // (deterministic now that rank is deterministic)
    {
        int lane32 = rank & 31;
        for (int a = 1; a < c; a++) {
            unsigned short iv = iout[a];
            float          vv = vout[a];
            int key = (((int)(iv >> 2)) - lane32) & 31;
            int p = a - 1;
            while (p >= 0 && (((((int)(iout[p] >> 2)) - lane32) & 31) > key)) {
                iout[p + 1] = iout[p];
                vout[p + 1] = vout[p];
                p--;
            }
            iout[p + 1] = iv;
            vout[p + 1] = vv;
        }
    }

    // w_inT[k][n] = w_in[n][k]  (n = tid)
    for (int kk = 0; kk < IN_DIM; kk++)
        w_inT[kk * HID + tid] = w_in[tid * IN_DIM + kk];
    // fcT[k][o] = fc_w[o][k]  (k = tid)
    for (int o = 0; o < OUT_DIM; o++)
        fcT[tid * OUT_DIM + o] = fc_w[o * HID + tid];
}

// ============================================================
// K1: xd[m][h] = x[m]@w_in^T + b_in + b_h  into activity slab.
//     Grid 16000 = 1000 m-tiles x 16 n-chunks (XCD-swizzled so the
//     16 n-blocks of one m-tile land on one XCD -> x L2-resident).
//     k-tile 32 in LDS (33 KB -> 4 blocks/CU, 16 waves/CU).
// ============================================================
__global__ __launch_bounds__(256, 4) void ingemm_kernel(
    const float* __restrict__ x, const float* __restrict__ w_inT,
    const float* __restrict__ b_in, const float* __restrict__ b_h,
    float* __restrict__ xd)
{
    __shared__ float xl[256 * 33];   // [row][33] pad -> (tid+kk)%32 banks, 2-way
    int tid = threadIdx.x;
    // de-swizzle: B = r8 + 8*(nc + 16*a); mb = 8a + r8 -> B%8 == mb%8
    int B  = blockIdx.x;
    int r8 = B & 7;
    int tt = B >> 3;
    int nc = tt & 15;
    int aa = tt >> 4;
    int mb = 8 * aa + r8;            // 0..999
    long m0 = (long)mb * 256;
    int n0 = nc * 32;

    float acc[32];
#pragma unroll
    for (int j = 0; j < 32; j++) acc[j] = b_in[n0 + j] + b_h[n0 + j];

    for (int k0 = 0; k0 < IN_DIM; k0 += 32) {
        __syncthreads();
#pragma unroll
        for (int i = 0; i < 8; i++) {
            int f  = tid + i * 256;      // 0..2047 float4s
            int rr = f >> 3, cc = f & 7;
            float4 v = *(const float4*)(x + (m0 + rr) * IN_DIM + k0 + cc * 4);
            float* d = &xl[rr * 33 + cc * 4];   // 132B rows: scalar writes (align)
            d[0] = v.x; d[1] = v.y; d[2] = v.z; d[3] = v.w;
        }
        __syncthreads();
        const float* xrow = &xl[tid * 33];
#pragma unroll
        for (int kk = 0; kk < 32; kk++) {
            float a = xrow[kk];
            const float* wrow = w_inT + (k0 + kk) * HID + n0;  // uniform -> s_load
#pragma unroll
            for (int j = 0; j < 32; j++) acc[j] = fmaf(a, wrow[j], acc[j]);
        }
    }
    float* orow = xd + (m0 + tid) * HID + n0;
#pragma unroll
    for (int j = 0; j < 8; j++)
        *(float4*)(orow + j * 4) =
            make_float4(acc[4*j], acc[4*j+1], acc[4*j+2], acc[4*j+3]);
}

// ============================================================
// K3: the scan. 256 blocks (one batch row each) x 512 threads.
//     Sparse w_eff row in REGISTERS (all-static indexing via
//     fallthrough switch on wave-uniform chunk count), act vector
//     double-buffered in LDS. Gather order is bank-rotation-sorted
//     (build pass 3) to cut LDS conflicts.
// ============================================================

// one packed pair: 2 gathers + 2 fmas, indices compile-time constant
#define PAIR2(base, ii)                                              \
    {                                                                \
        unsigned int pk = idp[ii];                                   \
        float g0 = *(const float*)((base) + (pk & 0xffffu));         \
        float g1 = *(const float*)((base) + (pk >> 16));             \
        a0 = fmaf(val[2*(ii)],     g0, a0);                          \
        a1 = fmaf(val[2*(ii) + 1], g1, a1);                          \
    }

#define CHUNK4(base, c)                                              \
    PAIR2(base, 4*(c)+0) PAIR2(base, 4*(c)+1)                        \
    PAIR2(base, 4*(c)+2) PAIR2(base, 4*(c)+3)

// accumulate a0+a1 over nch chunks (8 elements each), descending
// chunk order via fallthrough — every array index is a literal.
__device__ __forceinline__ float sparse_accum(
    const char* base, const float (&val)[MAXNNZ],
    const unsigned int (&idp)[MAXNNZ / 2], int nch, float a_init)
{
    float a0 = a_init, a1 = 0.f;
    switch (nch) {
        case 12: CHUNK4(base, 11) [[fallthrough]];
        case 11: CHUNK4(base, 10) [[fallthrough]];
        case 10: CHUNK4(base,  9) [[fallthrough]];
        case  9: CHUNK4(base,  8) [[fallthrough]];
        case  8: CHUNK4(base,  7) [[fallthrough]];
        case  7: CHUNK4(base,  6) [[fallthrough]];
        case  6: CHUNK4(base,  5) [[fallthrough]];
        case  5: CHUNK4(base,  4) [[fallthrough]];
        case  4: CHUNK4(base,  3) [[fallthrough]];
        case  3: CHUNK4(base,  2) [[fallthrough]];
        case  2: CHUNK4(base,  1) [[fallthrough]];
        case  1: CHUNK4(base,  0) break;
        default: break;
    }
    return a0 + a1;
}

__global__ __launch_bounds__(512, 2) void scan_kernel(
    float* __restrict__ act_g,
    const float* __restrict__ val_t, const unsigned short* __restrict__ idx_t,
    const unsigned int* __restrict__ perm, const unsigned int* __restrict__ nnzR)
{
    int tid = threadIdx.x;       // rank r
    int b   = blockIdx.x;
    __shared__ float sbuf[1024];  // [0..511] region0, [512..1023] region1
    sbuf[tid] = 0.f;

    // load this rank's table into registers (static indexing only)
    float        val[MAXNNZ];
    unsigned int idp[MAXNNZ / 2];
    {
        const float4* vp = (const float4*)(val_t + tid * MAXNNZ);
#pragma unroll
        for (int i = 0; i < MAXNNZ / 4; i++) {
            float4 v = vp[i];
            val[4*i] = v.x; val[4*i+1] = v.y; val[4*i+2] = v.z; val[4*i+3] = v.w;
        }
        const uint4* ip = (const uint4*)(idx_t + tid * MAXNNZ); // 96 u16 = 12 uint4
#pragma unroll
        for (int i = 0; i < MAXNNZ / 8; i++) {
            uint4 u = ip[i];
            idp[4*i] = u.x; idp[4*i+1] = u.y; idp[4*i+2] = u.z; idp[4*i+3] = u.w;
        }
    }
    int h = (int)perm[tid];
    int wmax = (int)nnzR[tid | 63];                 // sorted ascending -> wave max
    wmax = __builtin_amdgcn_readfirstlane(wmax);
    int nch = (wmax + 7) >> 3;                      // chunks of 8 elems (4 pairs)

    float state = 0.f;
    int gi = b * HID + h;                           // index of (t=0, b, h)
    float xdv = act_g[gi];                          // prefetch t=0
    const char* sb = (const char*)sbuf;
    __syncthreads();

    for (int t = 0; t < T_STEPS; t += 2) {
        { // even step: read region0, write region1
            float xn = act_g[gi + BATCH * HID];     // t+1 <= 999 always here
            float a = sparse_accum(sb, val, idp, nch, xdv);
            state = state * OMA_F + a * ALPHA_F;
            float act = fmaxf(state, 0.f);
            sbuf[512 + h] = act;
            act_g[gi] = act;
            gi += BATCH * HID;
            xdv = xn;
            __syncthreads();
        }
        { // odd step: read region1 (+2048B), write region0
            int gn = (t < T_STEPS - 2) ? gi + BATCH * HID : gi;
            float xn = act_g[gn];
            float a = sparse_accum(sb + 2048, val, idp, nch, xdv);
            state = state * OMA_F + a * ALPHA_F;
            float act = fmaxf(state, 0.f);
            sbuf[h] = act;
            act_g[gi] = act;
            gi += BATCH * HID;
            xdv = xn;
            __syncthreads();
        }
    }
}

// ============================================================
// K4: out[m][o] = act[m]@fc_w^T + fc_b. k-tile 32 in LDS
//     (33 KB -> 4 blocks/CU), uniform s_load weights.
// ============================================================
__global__ __launch_bounds__(256, 4) void outgemm_kernel(
    const float* __restrict__ act_g, const float* __restrict__ fcT,
    const float* __restrict__ fc_b, float* __restrict__ out_g)
{
    __shared__ float al[256 * 33];
    int tid = threadIdx.x;
    long m0 = (long)blockIdx.x * 256;

    float acc[32];
#pragma unroll
    for (int o = 0; o < 32; o++) acc[o] = fc_b[o];

    for (int k0 = 0; k0 < HID; k0 += 32) {
        __syncthreads();
#pragma unroll
        for (int i = 0; i < 8; i++) {
            int f  = tid + i * 256;      // 0..2047 float4s
            int rr = f >> 3, cc = f & 7;
            float4 v = *(const float4*)(act_g + (m0 + rr) * HID + k0 + cc * 4);
            float* d = &al[rr * 33 + cc * 4];
            d[0] = v.x; d[1] = v.y; d[2] = v.z; d[3] = v.w;
        }
        __syncthreads();
        const float* arow = &al[tid * 33];
#pragma unroll
        for (int kk = 0; kk < 32; kk++) {
            float a = arow[kk];
            const float* frow = fcT + (k0 + kk) * OUT_DIM;  // uniform -> s_load
#pragma unroll
            for (int o = 0; o < 32; o++) acc[o] = fmaf(a, frow[o], acc[o]);
        }
    }
    float* orow = out_g + (m0 + tid) * OUT_DIM;
#pragma unroll
    for (int j = 0; j < 8; j++)
        *(float4*)(orow + j * 4) =
            make_float4(acc[4*j], acc[4*j+1], acc[4*j+2], acc[4*j+3]);
}

// ============================================================
extern "C" void kernel_launch(void* const* d_in, const int* in_sizes, int n_in,
                              void* d_out, int out_size, void* d_ws, size_t ws_size,
                              hipStream_t stream)
{
    const float* x      = (const float*)d_in[0];
    const float* w_in   = (const float*)d_in[1];
    const float* b_in   = (const float*)d_in[2];
    const float* w_h    = (const float*)d_in[3];
    const float* b_h    = (const float*)d_in[4];
    const float* dale   = (const float*)d_in[5];
    const float* sparse = (const float*)d_in[6];
    const float* fc_w   = (const float*)d_in[7];
    const float* fc_b   = (const float*)d_in[8];

    float* out_g = (float*)d_out;
    float* act_g = out_g + (long)T_STEPS * BATCH * OUT_DIM;  // rnn_activity slab

    char* ws = (char*)d_ws;
    float*          val_t = (float*)(ws + 0);
    unsigned short* idx_t = (unsigned short*)(ws + 196608);
    unsigned int*   perm  = (unsigned int*)(ws + 294912);
    unsigned int*   nnzR  = (unsigned int*)(ws + 296960);
    float*          w_inT = (float*)(ws + 299008);
    float*          fcT   = (float*)(ws + 561152);

    build_kernel<<<1, 512, 0, stream>>>(w_h, dale, sparse, w_in, fc_w,
                                        val_t, idx_t, perm, nnzR, w_inT, fcT);
    ingemm_kernel<<<16000, 256, 0, stream>>>(x, w_inT, b_in, b_h, act_g);
    scan_kernel<<<256, 512, 0, stream>>>(act_g, val_t, idx_t, perm, nnzR);
    outgemm_kernel<<<1000, 256, 0, stream>>>(act_g, fcT, fc_b, out_g);
}

// Round 5
// 2081.483 us; speedup vs baseline: 1.7084x; 1.7084x over previous
//
#include <hip/hip_runtime.h>

#define T_STEPS 1000
#define BATCH   256
#define IN_DIM  128
#define HID     512
#define OUT_DIM 32
#define ALPHA_F 0.2f
#define OMA_F   0.8f
#define MAXNNZ  96   // Binomial(511,0.1) max over 512 rows ~ 75; 96 is 6.5 sigma

// ---- workspace layout (byte offsets, all 16B aligned) ----
// val_t : float  [HID][MAXNNZ]   rank-ordered rows      @ 0        (196608 B)
// idx_t : ushort [HID][MAXNNZ]   byte offsets (j*4)     @ 196608   (98304 B)
// perm  : uint   [HID]           rank -> row            @ 294912   (2048 B)
// nnzR  : uint   [HID]           nnz sorted ascending   @ 296960   (2048 B)
// w_inT : float  [IN_DIM][HID]                          @ 299008   (262144 B)
// fcT   : float  [HID][OUT_DIM]                         @ 561152   (65536 B)

// ============================================================
// K2a: counts + deterministic rank (stable sort by (c, h)).
// ============================================================
__global__ __launch_bounds__(512) void build_rank_kernel(
    const float* __restrict__ w_h, const float* __restrict__ sparse,
    unsigned int* __restrict__ perm, unsigned int* __restrict__ nnzR)
{
    int tid = threadIdx.x;           // row h
    __shared__ int cnt_sh[HID];

    const float4* wr4 = (const float4*)(w_h    + tid * HID);
    const float4* sr4 = (const float4*)(sparse + tid * HID);
    int cnt = 0;
    for (int j4 = 0; j4 < HID / 4; j4++) {
        float4 w = wr4[j4];
        float4 s = sr4[j4];
        if (w.x > 0.f && s.x > 0.5f) cnt++;
        if (w.y > 0.f && s.y > 0.5f) cnt++;
        if (w.z > 0.f && s.z > 0.5f) cnt++;
        if (w.w > 0.f && s.w > 0.5f) cnt++;
    }
    int c = min(cnt, MAXNNZ);

    cnt_sh[tid] = c;
    __syncthreads();
    int rank = 0;
    for (int j = 0; j < HID; j++) {
        int cj = cnt_sh[j];                     // broadcast read
        rank += (cj < c) || (cj == c && j < tid);
    }
    perm[rank] = (unsigned int)tid;
    nnzR[rank] = (unsigned int)c;
}

// ============================================================
// K2b: wave-parallel fill: one rank per block (1 wave). Counting
//      sort by bank-rotation key k = (j - (rank&31)) & 31, stable
//      in j within a bucket (identical order to the old stable
//      insertion sort). Deterministic: ballot order is lane order.
// ============================================================
__global__ __launch_bounds__(64) void fill_kernel(
    const float* __restrict__ w_h, const float* __restrict__ dale,
    const float* __restrict__ sparse,
    const unsigned int* __restrict__ perm, const unsigned int* __restrict__ nnzR,
    float* __restrict__ val_t, unsigned short* __restrict__ idx_t)
{
    int r    = blockIdx.x;           // rank
    int lane = threadIdx.x;          // 0..63
    int h = (int)perm[r];
    int c = (int)nnzR[r];
    int lane32 = r & 31;

    float*          vout = val_t + r * MAXNNZ;
    unsigned short* iout = idx_t + r * MAXNNZ;

    // zero the padding region [c..MAXNNZ)
    for (int k = lane; k < MAXNNZ; k += 64)
        if (k >= c) { vout[k] = 0.f; iout[k] = 0; }

    bool  pred[8];
    int   key[8];
    float wv[8];
    int   cnt[32];
#pragma unroll
    for (int k = 0; k < 32; k++) cnt[k] = 0;

    // pass A: per-key totals (wave-uniform ballots)
#pragma unroll
    for (int ch = 0; ch < 8; ch++) {
        int j = ch * 64 + lane;
        float w = w_h[h * HID + j];
        float s = sparse[h * HID + j];
        pred[ch] = (w > 0.f) && (s > 0.5f);
        key[ch]  = (j - lane32) & 31;
        wv[ch]   = w;
#pragma unroll
        for (int k = 0; k < 32; k++) {
            unsigned long long km = __ballot(pred[ch] && (key[ch] == k));
            cnt[k] += (int)__popcll(km);
        }
    }
    int base[32];
    {
        int a = 0;
#pragma unroll
        for (int k = 0; k < 32; k++) { base[k] = a; a += cnt[k]; }
    }

    // pass B: place (stable within bucket by j)
    unsigned long long lt = (1ull << lane) - 1ull;
#pragma unroll
    for (int ch = 0; ch < 8; ch++) {
        int j = ch * 64 + lane;
        int pos = -1;
#pragma unroll
        for (int k = 0; k < 32; k++) {
            unsigned long long km = __ballot(pred[ch] && (key[ch] == k));
            if (pred[ch] && key[ch] == k)
                pos = base[k] + (int)__popcll(km & lt);
            base[k] += (int)__popcll(km);
        }
        if (pred[ch] && pos < MAXNNZ) {
            vout[pos] = wv[ch] * dale[j];
            iout[pos] = (unsigned short)(j * 4);   // LDS byte offset
        }
    }
}

// ============================================================
// K2c: weight transposes, grid-parallel.
//      elems [0, 65536) -> w_inT, [65536, 81920) -> fcT
// ============================================================
__global__ __launch_bounds__(256) void trans_kernel(
    const float* __restrict__ w_in, const float* __restrict__ fc_w,
    float* __restrict__ w_inT, float* __restrict__ fcT)
{
    int o = blockIdx.x * 256 + threadIdx.x;
    if (o < IN_DIM * HID) {
        int k = o / HID, n = o % HID;          // w_inT[k][n] = w_in[n][k]
        w_inT[o] = w_in[n * IN_DIM + k];
    } else {
        int o2 = o - IN_DIM * HID;
        if (o2 < HID * OUT_DIM) {
            int k = o2 / OUT_DIM, oo = o2 % OUT_DIM;   // fcT[k][o] = fc_w[o][k]
            fcT[o2] = fc_w[oo * HID + k];
        }
    }
}

// ============================================================
// K1: xd[m][h] = x[m]@w_in^T + b_in + b_h  into activity slab.
//     Grid 16000 = 1000 m-tiles x 16 n-chunks (XCD-swizzled).
//     k-tile 32 in LDS (33 KB -> 4 blocks/CU, 16 waves/CU).
// ============================================================
__global__ __launch_bounds__(256, 4) void ingemm_kernel(
    const float* __restrict__ x, const float* __restrict__ w_inT,
    const float* __restrict__ b_in, const float* __restrict__ b_h,
    float* __restrict__ xd)
{
    __shared__ float xl[256 * 33];   // [row][33] pad -> (tid+kk)%32 banks, 2-way
    int tid = threadIdx.x;
    // de-swizzle: B = r8 + 8*(nc + 16*a); mb = 8a + r8 -> B%8 == mb%8
    int B  = blockIdx.x;
    int r8 = B & 7;
    int tt = B >> 3;
    int nc = tt & 15;
    int aa = tt >> 4;
    int mb = 8 * aa + r8;            // 0..999
    long m0 = (long)mb * 256;
    int n0 = nc * 32;

    float acc[32];
#pragma unroll
    for (int j = 0; j < 32; j++) acc[j] = b_in[n0 + j] + b_h[n0 + j];

    for (int k0 = 0; k0 < IN_DIM; k0 += 32) {
        __syncthreads();
#pragma unroll
        for (int i = 0; i < 8; i++) {
            int f  = tid + i * 256;      // 0..2047 float4s
            int rr = f >> 3, cc = f & 7;
            float4 v = *(const float4*)(x + (m0 + rr) * IN_DIM + k0 + cc * 4);
            float* d = &xl[rr * 33 + cc * 4];   // 132B rows: scalar writes (align)
            d[0] = v.x; d[1] = v.y; d[2] = v.z; d[3] = v.w;
        }
        __syncthreads();
        const float* xrow = &xl[tid * 33];
#pragma unroll
        for (int kk = 0; kk < 32; kk++) {
            float a = xrow[kk];
            const float* wrow = w_inT + (k0 + kk) * HID + n0;  // uniform -> s_load
#pragma unroll
            for (int j = 0; j < 32; j++) acc[j] = fmaf(a, wrow[j], acc[j]);
        }
    }
    float* orow = xd + (m0 + tid) * HID + n0;
#pragma unroll
    for (int j = 0; j < 8; j++)
        *(float4*)(orow + j * 4) =
            make_float4(acc[4*j], acc[4*j+1], acc[4*j+2], acc[4*j+3]);
}

// ============================================================
// K3: the scan. 256 blocks (one batch row each) x 512 threads.
//     Sparse w_eff row in REGISTERS (all-static indexing via
//     fallthrough switch on wave-uniform chunk count), act vector
//     double-buffered in LDS. Gather order bank-rotation-sorted.
// ============================================================

// one packed pair: 2 gathers + 2 fmas, indices compile-time constant
#define PAIR2(base, ii)                                              \
    {                                                                \
        unsigned int pk = idp[ii];                                   \
        float g0 = *(const float*)((base) + (pk & 0xffffu));         \
        float g1 = *(const float*)((base) + (pk >> 16));             \
        a0 = fmaf(val[2*(ii)],     g0, a0);                          \
        a1 = fmaf(val[2*(ii) + 1], g1, a1);                          \
    }

#define CHUNK4(base, c)                                              \
    PAIR2(base, 4*(c)+0) PAIR2(base, 4*(c)+1)                        \
    PAIR2(base, 4*(c)+2) PAIR2(base, 4*(c)+3)

// accumulate a0+a1 over nch chunks (8 elements each), descending
// chunk order via fallthrough — every array index is a literal.
__device__ __forceinline__ float sparse_accum(
    const char* base, const float (&val)[MAXNNZ],
    const unsigned int (&idp)[MAXNNZ / 2], int nch, float a_init)
{
    float a0 = a_init, a1 = 0.f;
    switch (nch) {
        case 12: CHUNK4(base, 11) [[fallthrough]];
        case 11: CHUNK4(base, 10) [[fallthrough]];
        case 10: CHUNK4(base,  9) [[fallthrough]];
        case  9: CHUNK4(base,  8) [[fallthrough]];
        case  8: CHUNK4(base,  7) [[fallthrough]];
        case  7: CHUNK4(base,  6) [[fallthrough]];
        case  6: CHUNK4(base,  5) [[fallthrough]];
        case  5: CHUNK4(base,  4) [[fallthrough]];
        case  4: CHUNK4(base,  3) [[fallthrough]];
        case  3: CHUNK4(base,  2) [[fallthrough]];
        case  2: CHUNK4(base,  1) [[fallthrough]];
        case  1: CHUNK4(base,  0) break;
        default: break;
    }
    return a0 + a1;
}

__global__ __launch_bounds__(512, 2) void scan_kernel(
    float* __restrict__ act_g,
    const float* __restrict__ val_t, const unsigned short* __restrict__ idx_t,
    const unsigned int* __restrict__ perm, const unsigned int* __restrict__ nnzR)
{
    int tid = threadIdx.x;       // rank r
    int b   = blockIdx.x;
    __shared__ float sbuf[1024];  // [0..511] region0, [512..1023] region1
    sbuf[tid] = 0.f;

    // load this rank's table into registers (static indexing only)
    float        val[MAXNNZ];
    unsigned int idp[MAXNNZ / 2];
    {
        const float4* vp = (const float4*)(val_t + tid * MAXNNZ);
#pragma unroll
        for (int i = 0; i < MAXNNZ / 4; i++) {
            float4 v = vp[i];
            val[4*i] = v.x; val[4*i+1] = v.y; val[4*i+2] = v.z; val[4*i+3] = v.w;
        }
        const uint4* ip = (const uint4*)(idx_t + tid * MAXNNZ); // 96 u16 = 12 uint4
#pragma unroll
        for (int i = 0; i < MAXNNZ / 8; i++) {
            uint4 u = ip[i];
            idp[4*i] = u.x; idp[4*i+1] = u.y; idp[4*i+2] = u.z; idp[4*i+3] = u.w;
        }
    }
    int h = (int)perm[tid];
    int wmax = (int)nnzR[tid | 63];                 // sorted ascending -> wave max
    wmax = __builtin_amdgcn_readfirstlane(wmax);
    int nch = (wmax + 7) >> 3;                      // chunks of 8 elems (4 pairs)

    float state = 0.f;
    int gi = b * HID + h;                           // index of (t=0, b, h)
    float xdv = act_g[gi];                          // prefetch t=0
    const char* sb = (const char*)sbuf;
    __syncthreads();

    for (int t = 0; t < T_STEPS; t += 2) {
        { // even step: read region0, write region1
            float xn = act_g[gi + BATCH * HID];     // t+1 <= 999 always here
            float a = sparse_accum(sb, val, idp, nch, xdv);
            state = state * OMA_F + a * ALPHA_F;
            float act = fmaxf(state, 0.f);
            sbuf[512 + h] = act;
            act_g[gi] = act;
            gi += BATCH * HID;
            xdv = xn;
            __syncthreads();
        }
        { // odd step: read region1 (+2048B), write region0
            int gn = (t < T_STEPS - 2) ? gi + BATCH * HID : gi;
            float xn = act_g[gn];
            float a = sparse_accum(sb + 2048, val, idp, nch, xdv);
            state = state * OMA_F + a * ALPHA_F;
            float act = fmaxf(state, 0.f);
            sbuf[h] = act;
            act_g[gi] = act;
            gi += BATCH * HID;
            xdv = xn;
            __syncthreads();
        }
    }
}

// ============================================================
// K4: out[m][o] = act[m]@fc_w^T + fc_b. k-tile 32 in LDS
//     (33 KB -> 4 blocks/CU), uniform s_load weights.
// ============================================================
__global__ __launch_bounds__(256, 4) void outgemm_kernel(
    const float* __restrict__ act_g, const float* __restrict__ fcT,
    const float* __restrict__ fc_b, float* __restrict__ out_g)
{
    __shared__ float al[256 * 33];
    int tid = threadIdx.x;
    long m0 = (long)blockIdx.x * 256;

    float acc[32];
#pragma unroll
    for (int o = 0; o < 32; o++) acc[o] = fc_b[o];

    for (int k0 = 0; k0 < HID; k0 += 32) {
        __syncthreads();
#pragma unroll
        for (int i = 0; i < 8; i++) {
            int f  = tid + i * 256;      // 0..2047 float4s
            int rr = f >> 3, cc = f & 7;
            float4 v = *(const float4*)(act_g + (m0 + rr) * HID + k0 + cc * 4);
            float* d = &al[rr * 33 + cc * 4];
            d[0] = v.x; d[1] = v.y; d[2] = v.z; d[3] = v.w;
        }
        __syncthreads();
        const float* arow = &al[tid * 33];
#pragma unroll
        for (int kk = 0; kk < 32; kk++) {
            float a = arow[kk];
            const float* frow = fcT + (k0 + kk) * OUT_DIM;  // uniform -> s_load
#pragma unroll
            for (int o = 0; o < 32; o++) acc[o] = fmaf(a, frow[o], acc[o]);
        }
    }
    float* orow = out_g + (m0 + tid) * OUT_DIM;
#pragma unroll
    for (int j = 0; j < 8; j++)
        *(float4*)(orow + j * 4) =
            make_float4(acc[4*j], acc[4*j+1], acc[4*j+2], acc[4*j+3]);
}

// ============================================================
extern "C" void kernel_launch(void* const* d_in, const int* in_sizes, int n_in,
                              void* d_out, int out_size, void* d_ws, size_t ws_size,
                              hipStream_t stream)
{
    const float* x      = (const float*)d_in[0];
    const float* w_in   = (const float*)d_in[1];
    const float* b_in   = (const float*)d_in[2];
    const float* w_h    = (const float*)d_in[3];
    const float* b_h    = (const float*)d_in[4];
    const float* dale   = (const float*)d_in[5];
    const float* sparse = (const float*)d_in[6];
    const float* fc_w   = (const float*)d_in[7];
    const float* fc_b   = (const float*)d_in[8];

    float* out_g = (float*)d_out;
    float* act_g = out_g + (long)T_STEPS * BATCH * OUT_DIM;  // rnn_activity slab

    char* ws = (char*)d_ws;
    float*          val_t = (float*)(ws + 0);
    unsigned short* idx_t = (unsigned short*)(ws + 196608);
    unsigned int*   perm  = (unsigned int*)(ws + 294912);
    unsigned int*   nnzR  = (unsigned int*)(ws + 296960);
    float*          w_inT = (float*)(ws + 299008);
    float*          fcT   = (float*)(ws + 561152);

    build_rank_kernel<<<1, 512, 0, stream>>>(w_h, sparse, perm, nnzR);
    fill_kernel<<<HID, 64, 0, stream>>>(w_h, dale, sparse, perm, nnzR, val_t, idx_t);
    trans_kernel<<<320, 256, 0, stream>>>(w_in, fc_w, w_inT, fcT);
    ingemm_kernel<<<16000, 256, 0, stream>>>(x, w_inT, b_in, b_h, act_g);
    scan_kernel<<<256, 512, 0, stream>>>(act_g, val_t, idx_t, perm, nnzR);
    outgemm_kernel<<<1000, 256, 0, stream>>>(act_g, fcT, fc_b, out_g);
}

// Round 6
// 2046.139 us; speedup vs baseline: 1.7379x; 1.0173x over previous
//
#include <hip/hip_runtime.h>

#define T_STEPS 1000
#define BATCH   256
#define IN_DIM  128
#define HID     512
#define OUT_DIM 32
#define ALPHA_F 0.2f
#define OMA_F   0.8f
#define MAXNNZ  96   // Binomial(511,0.1) max over 512 rows ~ 75; 96 is 6.5 sigma

// ---- workspace layout (byte offsets, all 16B aligned) ----
// val_t : float  [HID][MAXNNZ]   rank-ordered rows      @ 0        (196608 B)
// idx_t : ushort [HID][MAXNNZ]   byte offsets (j*4)     @ 196608   (98304 B)
// perm  : uint   [HID]           rank -> row            @ 294912   (2048 B)
// nnzR  : uint   [HID]           nnz sorted ascending   @ 296960   (2048 B)
// w_inT : float  [IN_DIM][HID]                          @ 299008   (262144 B)
// fcT   : float  [HID][OUT_DIM]                         @ 561152   (65536 B)

// ============================================================
// K2a: counts + deterministic rank (stable sort by (c, h)).
// ============================================================
__global__ __launch_bounds__(512) void build_rank_kernel(
    const float* __restrict__ w_h, const float* __restrict__ sparse,
    unsigned int* __restrict__ perm, unsigned int* __restrict__ nnzR)
{
    int tid = threadIdx.x;           // row h
    __shared__ int cnt_sh[HID];

    const float4* wr4 = (const float4*)(w_h    + tid * HID);
    const float4* sr4 = (const float4*)(sparse + tid * HID);
    int cnt = 0;
    for (int j4 = 0; j4 < HID / 4; j4++) {
        float4 w = wr4[j4];
        float4 s = sr4[j4];
        if (w.x > 0.f && s.x > 0.5f) cnt++;
        if (w.y > 0.f && s.y > 0.5f) cnt++;
        if (w.z > 0.f && s.z > 0.5f) cnt++;
        if (w.w > 0.f && s.w > 0.5f) cnt++;
    }
    int c = min(cnt, MAXNNZ);

    cnt_sh[tid] = c;
    __syncthreads();
    int rank = 0;
    for (int j = 0; j < HID; j++) {
        int cj = cnt_sh[j];                     // broadcast read
        rank += (cj < c) || (cj == c && j < tid);
    }
    perm[rank] = (unsigned int)tid;
    nnzR[rank] = (unsigned int)c;
}

// ============================================================
// K2b: wave-parallel fill, one rank per block (1 wave).
//      Ascending-j compaction via ballot prefix (deterministic,
//      identical order to Round-2's stable fill). Natural order
//      measured BETTER for LDS conflicts than bank-rotation sort
//      (3.45e8 vs 4.33e8 conflict counts).
// ============================================================
__global__ __launch_bounds__(64) void fill_kernel(
    const float* __restrict__ w_h, const float* __restrict__ dale,
    const float* __restrict__ sparse,
    const unsigned int* __restrict__ perm, const unsigned int* __restrict__ nnzR,
    float* __restrict__ val_t, unsigned short* __restrict__ idx_t)
{
    int r    = blockIdx.x;           // rank
    int lane = threadIdx.x;          // 0..63
    int h = (int)perm[r];
    int c = (int)nnzR[r];

    float*          vout = val_t + r * MAXNNZ;
    unsigned short* iout = idx_t + r * MAXNNZ;

    // zero the padding region [c..MAXNNZ)
    for (int k = lane; k < MAXNNZ; k += 64)
        if (k >= c) { vout[k] = 0.f; iout[k] = 0; }

    unsigned long long lt = (1ull << lane) - 1ull;
    int pos_base = 0;
#pragma unroll
    for (int ch = 0; ch < 8; ch++) {
        int j = ch * 64 + lane;
        float w = w_h[h * HID + j];
        float s = sparse[h * HID + j];
        bool pred = (w > 0.f) && (s > 0.5f);
        unsigned long long m = __ballot(pred);
        if (pred) {
            int pos = pos_base + (int)__popcll(m & lt);
            if (pos < MAXNNZ) {
                vout[pos] = w * dale[j];
                iout[pos] = (unsigned short)(j * 4);   // LDS byte offset
            }
        }
        pos_base += (int)__popcll(m);
    }
}

// ============================================================
// K2c: weight transposes, grid-parallel.
// ============================================================
__global__ __launch_bounds__(256) void trans_kernel(
    const float* __restrict__ w_in, const float* __restrict__ fc_w,
    float* __restrict__ w_inT, float* __restrict__ fcT)
{
    int o = blockIdx.x * 256 + threadIdx.x;
    if (o < IN_DIM * HID) {
        int k = o / HID, n = o % HID;          // w_inT[k][n] = w_in[n][k]
        w_inT[o] = w_in[n * IN_DIM + k];
    } else {
        int o2 = o - IN_DIM * HID;
        if (o2 < HID * OUT_DIM) {
            int k = o2 / OUT_DIM, oo = o2 % OUT_DIM;   // fcT[k][o] = fc_w[o][k]
            fcT[o2] = fc_w[oo * HID + k];
        }
    }
}

// ============================================================
// K1: xd[m][h] = x[m]@w_in^T + b_in + b_h  into activity slab.
//     Grid 16000 = 1000 m-tiles x 16 n-chunks (XCD-swizzled).
//     k-tile 32 in LDS (33 KB -> 4 blocks/CU, 16 waves/CU).
// ============================================================
__global__ __launch_bounds__(256, 4) void ingemm_kernel(
    const float* __restrict__ x, const float* __restrict__ w_inT,
    const float* __restrict__ b_in, const float* __restrict__ b_h,
    float* __restrict__ xd)
{
    __shared__ float xl[256 * 33];   // [row][33] pad -> (tid+kk)%32 banks, 2-way
    int tid = threadIdx.x;
    // de-swizzle: B = r8 + 8*(nc + 16*a); mb = 8a + r8 -> B%8 == mb%8
    int B  = blockIdx.x;
    int r8 = B & 7;
    int tt = B >> 3;
    int nc = tt & 15;
    int aa = tt >> 4;
    int mb = 8 * aa + r8;            // 0..999
    long m0 = (long)mb * 256;
    int n0 = nc * 32;

    float acc[32];
#pragma unroll
    for (int j = 0; j < 32; j++) acc[j] = b_in[n0 + j] + b_h[n0 + j];

    for (int k0 = 0; k0 < IN_DIM; k0 += 32) {
        __syncthreads();
#pragma unroll
        for (int i = 0; i < 8; i++) {
            int f  = tid + i * 256;      // 0..2047 float4s
            int rr = f >> 3, cc = f & 7;
            float4 v = *(const float4*)(x + (m0 + rr) * IN_DIM + k0 + cc * 4);
            float* d = &xl[rr * 33 + cc * 4];   // 132B rows: scalar writes (align)
            d[0] = v.x; d[1] = v.y; d[2] = v.z; d[3] = v.w;
        }
        __syncthreads();
        const float* xrow = &xl[tid * 33];
#pragma unroll
        for (int kk = 0; kk < 32; kk++) {
            float a = xrow[kk];
            const float* wrow = w_inT + (k0 + kk) * HID + n0;  // uniform -> s_load
#pragma unroll
            for (int j = 0; j < 32; j++) acc[j] = fmaf(a, wrow[j], acc[j]);
        }
    }
    float* orow = xd + (m0 + tid) * HID + n0;
#pragma unroll
    for (int j = 0; j < 8; j++)
        *(float4*)(orow + j * 4) =
            make_float4(acc[4*j], acc[4*j+1], acc[4*j+2], acc[4*j+3]);
}

// ============================================================
// K3: the scan. 256 blocks (one batch row each) x 512 threads.
//     Sparse w_eff row in REGISTERS (all-static indexing via
//     fallthrough switch on wave-uniform chunk count; chunk=4
//     to cut rounding waste), act double-buffered in LDS.
// ============================================================

// one packed pair: 2 gathers + 2 fmas, indices compile-time constant
#define PAIR2(base, ii)                                              \
    {                                                                \
        unsigned int pk = idp[ii];                                   \
        float g0 = *(const float*)((base) + (pk & 0xffffu));         \
        float g1 = *(const float*)((base) + (pk >> 16));             \
        a0 = fmaf(val[2*(ii)],     g0, a0);                          \
        a1 = fmaf(val[2*(ii) + 1], g1, a1);                          \
    }

#define CHUNK2(base, c)                                              \
    PAIR2(base, 2*(c)+0) PAIR2(base, 2*(c)+1)

// accumulate a0+a1 over nch chunks (4 elements each), descending
// chunk order via fallthrough — every array index is a literal.
__device__ __forceinline__ float sparse_accum(
    const char* base, const float (&val)[MAXNNZ],
    const unsigned int (&idp)[MAXNNZ / 2], int nch, float a_init)
{
    float a0 = a_init, a1 = 0.f;
    switch (nch) {
        case 24: CHUNK2(base, 23) [[fallthrough]];
        case 23: CHUNK2(base, 22) [[fallthrough]];
        case 22: CHUNK2(base, 21) [[fallthrough]];
        case 21: CHUNK2(base, 20) [[fallthrough]];
        case 20: CHUNK2(base, 19) [[fallthrough]];
        case 19: CHUNK2(base, 18) [[fallthrough]];
        case 18: CHUNK2(base, 17) [[fallthrough]];
        case 17: CHUNK2(base, 16) [[fallthrough]];
        case 16: CHUNK2(base, 15) [[fallthrough]];
        case 15: CHUNK2(base, 14) [[fallthrough]];
        case 14: CHUNK2(base, 13) [[fallthrough]];
        case 13: CHUNK2(base, 12) [[fallthrough]];
        case 12: CHUNK2(base, 11) [[fallthrough]];
        case 11: CHUNK2(base, 10) [[fallthrough]];
        case 10: CHUNK2(base,  9) [[fallthrough]];
        case  9: CHUNK2(base,  8) [[fallthrough]];
        case  8: CHUNK2(base,  7) [[fallthrough]];
        case  7: CHUNK2(base,  6) [[fallthrough]];
        case  6: CHUNK2(base,  5) [[fallthrough]];
        case  5: CHUNK2(base,  4) [[fallthrough]];
        case  4: CHUNK2(base,  3) [[fallthrough]];
        case  3: CHUNK2(base,  2) [[fallthrough]];
        case  2: CHUNK2(base,  1) [[fallthrough]];
        case  1: CHUNK2(base,  0) break;
        default: break;
    }
    return a0 + a1;
}

__global__ __launch_bounds__(512, 2) void scan_kernel(
    float* __restrict__ act_g,
    const float* __restrict__ val_t, const unsigned short* __restrict__ idx_t,
    const unsigned int* __restrict__ perm, const unsigned int* __restrict__ nnzR)
{
    int tid = threadIdx.x;       // rank r
    int b   = blockIdx.x;
    __shared__ float sbuf[1024];  // [0..511] region0, [512..1023] region1
    sbuf[tid] = 0.f;

    // load this rank's table into registers (static indexing only)
    float        val[MAXNNZ];
    unsigned int idp[MAXNNZ / 2];
    {
        const float4* vp = (const float4*)(val_t + tid * MAXNNZ);
#pragma unroll
        for (int i = 0; i < MAXNNZ / 4; i++) {
            float4 v = vp[i];
            val[4*i] = v.x; val[4*i+1] = v.y; val[4*i+2] = v.z; val[4*i+3] = v.w;
        }
        const uint4* ip = (const uint4*)(idx_t + tid * MAXNNZ); // 96 u16 = 12 uint4
#pragma unroll
        for (int i = 0; i < MAXNNZ / 8; i++) {
            uint4 u = ip[i];
            idp[4*i] = u.x; idp[4*i+1] = u.y; idp[4*i+2] = u.z; idp[4*i+3] = u.w;
        }
    }
    int h = (int)perm[tid];
    int wmax = (int)nnzR[tid | 63];                 // sorted ascending -> wave max
    wmax = __builtin_amdgcn_readfirstlane(wmax);
    int nch = (wmax + 3) >> 2;                      // chunks of 4 elems (2 pairs)

    float state = 0.f;
    int gi = b * HID + h;                           // index of (t=0, b, h)
    float xdv = act_g[gi];                          // prefetch t=0
    const char* sb = (const char*)sbuf;
    __syncthreads();

    for (int t = 0; t < T_STEPS; t += 2) {
        { // even step: read region0, write region1
            float xn = act_g[gi + BATCH * HID];     // t+1 <= 999 always here
            float a = sparse_accum(sb, val, idp, nch, xdv);
            state = state * OMA_F + a * ALPHA_F;
            float act = fmaxf(state, 0.f);
            sbuf[512 + h] = act;
            act_g[gi] = act;
            gi += BATCH * HID;
            xdv = xn;
            __syncthreads();
        }
        { // odd step: read region1 (+2048B), write region0
            int gn = (t < T_STEPS - 2) ? gi + BATCH * HID : gi;
            float xn = act_g[gn];
            float a = sparse_accum(sb + 2048, val, idp, nch, xdv);
            state = state * OMA_F + a * ALPHA_F;
            float act = fmaxf(state, 0.f);
            sbuf[h] = act;
            act_g[gi] = act;
            gi += BATCH * HID;
            xdv = xn;
            __syncthreads();
        }
    }
}

// ============================================================
// K4: out[m][o] = act[m]@fc_w^T + fc_b. k-tile 32 in LDS
//     (33 KB -> 4 blocks/CU), uniform s_load weights.
// ============================================================
__global__ __launch_bounds__(256, 4) void outgemm_kernel(
    const float* __restrict__ act_g, const float* __restrict__ fcT,
    const float* __restrict__ fc_b, float* __restrict__ out_g)
{
    __shared__ float al[256 * 33];
    int tid = threadIdx.x;
    long m0 = (long)blockIdx.x * 256;

    float acc[32];
#pragma unroll
    for (int o = 0; o < 32; o++) acc[o] = fc_b[o];

    for (int k0 = 0; k0 < HID; k0 += 32) {
        __syncthreads();
#pragma unroll
        for (int i = 0; i < 8; i++) {
            int f  = tid + i * 256;      // 0..2047 float4s
            int rr = f >> 3, cc = f & 7;
            float4 v = *(const float4*)(act_g + (m0 + rr) * HID + k0 + cc * 4);
            float* d = &al[rr * 33 + cc * 4];
            d[0] = v.x; d[1] = v.y; d[2] = v.z; d[3] = v.w;
        }
        __syncthreads();
        const float* arow = &al[tid * 33];
#pragma unroll
        for (int kk = 0; kk < 32; kk++) {
            float a = arow[kk];
            const float* frow = fcT + (k0 + kk) * OUT_DIM;  // uniform -> s_load
#pragma unroll
            for (int o = 0; o < 32; o++) acc[o] = fmaf(a, frow[o], acc[o]);
        }
    }
    float* orow = out_g + (m0 + tid) * OUT_DIM;
#pragma unroll
    for (int j = 0; j < 8; j++)
        *(float4*)(orow + j * 4) =
            make_float4(acc[4*j], acc[4*j+1], acc[4*j+2], acc[4*j+3]);
}

// ============================================================
extern "C" void kernel_launch(void* const* d_in, const int* in_sizes, int n_in,
                              void* d_out, int out_size, void* d_ws, size_t ws_size,
                              hipStream_t stream)
{
    const float* x      = (const float*)d_in[0];
    const float* w_in   = (const float*)d_in[1];
    const float* b_in   = (const float*)d_in[2];
    const float* w_h    = (const float*)d_in[3];
    const float* b_h    = (const float*)d_in[4];
    const float* dale   = (const float*)d_in[5];
    const float* sparse = (const float*)d_in[6];
    const float* fc_w   = (const float*)d_in[7];
    const float* fc_b   = (const float*)d_in[8];

    float* out_g = (float*)d_out;
    float* act_g = out_g + (long)T_STEPS * BATCH * OUT_DIM;  // rnn_activity slab

    char* ws = (char*)d_ws;
    float*          val_t = (float*)(ws + 0);
    unsigned short* idx_t = (unsigned short*)(ws + 196608);
    unsigned int*   perm  = (unsigned int*)(ws + 294912);
    unsigned int*   nnzR  = (unsigned int*)(ws + 296960);
    float*          w_inT = (float*)(ws + 299008);
    float*          fcT   = (float*)(ws + 561152);

    build_rank_kernel<<<1, 512, 0, stream>>>(w_h, sparse, perm, nnzR);
    fill_kernel<<<HID, 64, 0, stream>>>(w_h, dale, sparse, perm, nnzR, val_t, idx_t);
    trans_kernel<<<320, 256, 0, stream>>>(w_in, fc_w, w_inT, fcT);
    ingemm_kernel<<<16000, 256, 0, stream>>>(x, w_inT, b_in, b_h, act_g);
    scan_kernel<<<256, 512, 0, stream>>>(act_g, val_t, idx_t, perm, nnzR);
    outgemm_kernel<<<1000, 256, 0, stream>>>(act_g, fcT, fc_b, out_g);
}